// Round 3
// baseline (245.674 us; speedup 1.0000x reference)
//
#include <hip/hip_runtime.h>

// relative_depth_crit — R2: MLP restructure. R1 was latency-bound at VGPR=16
// (compiler serialized the 8 gathers). Now: 2 vec4 items/thread, all 16 gather
// offsets computed first, 16 loads issued back-to-back into an array, one wait,
// then consume. Target: L2 request-rate floor ~42-50 us.

constexpr int B = 64;
constexpr int H = 512;
constexpr int W = 640;
constexpr int P = 100000;                 // divisible by 4
constexpr int N4B = P / 4;                // 25000 vec4 items per batch
constexpr int IPB = 512;                  // vec4 items per block (2 per thread)
constexpr int CHUNKS = (N4B + IPB - 1) / IPB;   // 49 blocks per batch
constexpr int NBLK = B * CHUNKS;          // 3136 = 8 * 392
constexpr float INV_N = 1.0f / (float)(B * P);
constexpr float MARGIN = 1.0f;

typedef int vint4 __attribute__((ext_vector_type(4)));

__device__ __forceinline__ float loss_from(float za, float zb, int od) {
    float zd = za - zb;
    float gt = (float)(od - 1);           // {-1, 0, 1}
    float mask = fabsf(gt);               // {0, 1}
    float t = fminf(gt * zd, MARGIN);
    float l_rank = __logf(1.0f + __expf(-t));
    float l_eq = fmaxf(zd * zd, MARGIN * MARGIN);
    return mask * l_rank + (1.0f - mask) * l_eq;
}

__global__ __launch_bounds__(256) void rdc_kernel(
        const float* __restrict__ depth,
        const vint4* __restrict__ xA, const vint4* __restrict__ yA,
        const vint4* __restrict__ xB, const vint4* __restrict__ yB,
        const vint4* __restrict__ ord,
        float* __restrict__ partials) {
    int j = blockIdx.x;
    // XCD-aware swizzle: j%8 ~ XCD id; each XCD sticks to batches b≡x (mod 8),
    // 49 consecutive block-groups per batch -> one 1.31 MB slab per XCD L2.
    int x = j & 7;
    int g = j >> 3;                       // 0..391
    int b = ((g / CHUNKS) << 3) + x;      // 0..63
    int c = g % CHUNKS;                   // 0..48
    int e0 = c * IPB + threadIdx.x;       // always < N4B (48*512+255 = 24831)
    int e1 = e0 + 256;                    // may exceed N4B only when c==48

    float s1 = (e1 < N4B) ? 1.0f : 0.0f;
    int i0 = b * N4B + e0;
    int i1 = b * N4B + (e1 < N4B ? e1 : e0);

    const float* d = depth + (size_t)b * (H * W);

    // ---- phase 1: stream the index vectors (read-once -> nontemporal) ----
    vint4 xa0 = __builtin_nontemporal_load(&xA[i0]);
    vint4 ya0 = __builtin_nontemporal_load(&yA[i0]);
    vint4 xb0 = __builtin_nontemporal_load(&xB[i0]);
    vint4 yb0 = __builtin_nontemporal_load(&yB[i0]);
    vint4 od0 = __builtin_nontemporal_load(&ord[i0]);
    vint4 xa1 = __builtin_nontemporal_load(&xA[i1]);
    vint4 ya1 = __builtin_nontemporal_load(&yA[i1]);
    vint4 xb1 = __builtin_nontemporal_load(&xB[i1]);
    vint4 yb1 = __builtin_nontemporal_load(&yB[i1]);
    vint4 od1 = __builtin_nontemporal_load(&ord[i1]);

    // ---- phase 2: all 16 gather offsets, then 16 loads in flight ----
    int off[16];
    off[0]  = ya0.x * W + xa0.x;  off[1]  = yb0.x * W + xb0.x;
    off[2]  = ya0.y * W + xa0.y;  off[3]  = yb0.y * W + xb0.y;
    off[4]  = ya0.z * W + xa0.z;  off[5]  = yb0.z * W + xb0.z;
    off[6]  = ya0.w * W + xa0.w;  off[7]  = yb0.w * W + xb0.w;
    off[8]  = ya1.x * W + xa1.x;  off[9]  = yb1.x * W + xb1.x;
    off[10] = ya1.y * W + xa1.y;  off[11] = yb1.y * W + xb1.y;
    off[12] = ya1.z * W + xa1.z;  off[13] = yb1.z * W + xb1.z;
    off[14] = ya1.w * W + xa1.w;  off[15] = yb1.w * W + xb1.w;

    float z[16];
    #pragma unroll
    for (int k = 0; k < 16; ++k)
        z[k] = d[off[k]];

    // ---- phase 3: consume ----
    float acc = 0.0f;
    acc += loss_from(z[0],  z[1],  od0.x);
    acc += loss_from(z[2],  z[3],  od0.y);
    acc += loss_from(z[4],  z[5],  od0.z);
    acc += loss_from(z[6],  z[7],  od0.w);
    float acc1 = 0.0f;
    acc1 += loss_from(z[8],  z[9],  od1.x);
    acc1 += loss_from(z[10], z[11], od1.y);
    acc1 += loss_from(z[12], z[13], od1.z);
    acc1 += loss_from(z[14], z[15], od1.w);
    acc += s1 * acc1;

    // ---- wave + block reduction ----
    #pragma unroll
    for (int off2 = 32; off2 > 0; off2 >>= 1)
        acc += __shfl_down(acc, off2, 64);

    __shared__ float wsum[4];
    int lane = threadIdx.x & 63;
    int wid  = threadIdx.x >> 6;
    if (lane == 0) wsum[wid] = acc;
    __syncthreads();
    if (wid == 0 && lane == 0)
        partials[j] = wsum[0] + wsum[1] + wsum[2] + wsum[3];
}

__global__ __launch_bounds__(256) void rdc_finalize(
        const float* __restrict__ partials, float* __restrict__ out, int n) {
    float acc = 0.0f;
    for (int k = threadIdx.x; k < n; k += 256)
        acc += partials[k];
    #pragma unroll
    for (int off = 32; off > 0; off >>= 1)
        acc += __shfl_down(acc, off, 64);
    __shared__ float wsum[4];
    int lane = threadIdx.x & 63;
    int wid  = threadIdx.x >> 6;
    if (lane == 0) wsum[wid] = acc;
    __syncthreads();
    if (wid == 0 && lane == 0)
        out[0] = (wsum[0] + wsum[1] + wsum[2] + wsum[3]) * INV_N;
}

extern "C" void kernel_launch(void* const* d_in, const int* in_sizes, int n_in,
                              void* d_out, int out_size, void* d_ws, size_t ws_size,
                              hipStream_t stream) {
    const float* depth = (const float*)d_in[0];
    const vint4* xA = (const vint4*)d_in[1];
    const vint4* yA = (const vint4*)d_in[2];
    const vint4* xB = (const vint4*)d_in[3];
    const vint4* yB = (const vint4*)d_in[4];
    const vint4* ord = (const vint4*)d_in[5];
    float* out = (float*)d_out;

    float* partials = (float*)d_ws;      // NBLK*4 = 12.5 KB, ws is plenty
    rdc_kernel<<<NBLK, 256, 0, stream>>>(depth, xA, yA, xB, yB, ord, partials);
    rdc_finalize<<<1, 256, 0, stream>>>(partials, out, NBLK);
}

// Round 4
// 241.944 us; speedup vs baseline: 1.0154x; 1.0154x over previous
//
#include <hip/hip_runtime.h>

// relative_depth_crit — R3: gather via buffer_load sc0 (L1 bypass).
// R1==R2 (88~90us) despite 2x software MLP => hardware per-CU outstanding-miss
// cap in L1/TCP is the suspected limit (~60 misses @ ~275cyc => 0.22/cyc => 95us).
// Depth gathers have ~2% L1 hit rate (1.31MB slab vs 32KB L1), so L1 only adds
// a bottleneck. sc0 loads bypass L1 and read L2 directly.

constexpr int B = 64;
constexpr int H = 512;
constexpr int W = 640;
constexpr int P = 100000;                 // divisible by 4
constexpr int N4B = P / 4;                // 25000 vec4 items per batch
constexpr int IPB = 512;                  // vec4 items per block (2 per thread)
constexpr int CHUNKS = (N4B + IPB - 1) / IPB;   // 49 blocks per batch
constexpr int NBLK = B * CHUNKS;          // 3136
constexpr int SLAB_BYTES = H * W * 4;     // 1,310,720
constexpr float INV_N = 1.0f / (float)(B * P);
constexpr float MARGIN = 1.0f;

typedef int vint4 __attribute__((ext_vector_type(4)));

__device__ __forceinline__ float loss_from(float za, float zb, int od) {
    float zd = za - zb;
    float gt = (float)(od - 1);           // {-1, 0, 1}
    float mask = fabsf(gt);               // {0, 1}
    float t = fminf(gt * zd, MARGIN);
    float l_rank = __logf(1.0f + __expf(-t));
    float l_eq = fmaxf(zd * zd, MARGIN * MARGIN);
    return mask * l_rank + (1.0f - mask) * l_eq;
}

__global__ __launch_bounds__(256) void rdc_kernel(
        const float* __restrict__ depth,
        const vint4* __restrict__ xA, const vint4* __restrict__ yA,
        const vint4* __restrict__ xB, const vint4* __restrict__ yB,
        const vint4* __restrict__ ord,
        float* __restrict__ partials) {
    int j = blockIdx.x;
    // XCD-aware swizzle: j%8 ~ XCD id; each XCD sticks to batches b≡x (mod 8).
    int x = j & 7;
    int g = j >> 3;
    int b = ((g / CHUNKS) << 3) + x;
    int c = g % CHUNKS;
    int e0 = c * IPB + threadIdx.x;       // < N4B always (48*512+255=24831)
    int e1 = e0 + 256;                    // may exceed N4B only when c==48

    float s1 = (e1 < N4B) ? 1.0f : 0.0f;
    int i0 = b * N4B + e0;
    int i1 = b * N4B + (e1 < N4B ? e1 : e0);

    // Per-batch buffer resource over the depth slab (block-uniform -> SGPRs).
    const float* slab = depth + (size_t)b * (H * W);
    __amdgpu_buffer_rsrc_t rsrc = __builtin_amdgcn_make_buffer_rsrc(
        (void*)slab, (short)0, SLAB_BYTES, 0x00020000);

    // ---- phase 1: stream index vectors (read-once -> nontemporal) ----
    vint4 xa0 = __builtin_nontemporal_load(&xA[i0]);
    vint4 ya0 = __builtin_nontemporal_load(&yA[i0]);
    vint4 xb0 = __builtin_nontemporal_load(&xB[i0]);
    vint4 yb0 = __builtin_nontemporal_load(&yB[i0]);
    vint4 od0 = __builtin_nontemporal_load(&ord[i0]);
    vint4 xa1 = __builtin_nontemporal_load(&xA[i1]);
    vint4 ya1 = __builtin_nontemporal_load(&yA[i1]);
    vint4 xb1 = __builtin_nontemporal_load(&xB[i1]);
    vint4 yb1 = __builtin_nontemporal_load(&yB[i1]);
    vint4 od1 = __builtin_nontemporal_load(&ord[i1]);

    // ---- phase 2: 16 byte-offsets, then 16 sc0 (L1-bypass) loads ----
    int off[16];
    off[0]  = (ya0.x * W + xa0.x) << 2;  off[1]  = (yb0.x * W + xb0.x) << 2;
    off[2]  = (ya0.y * W + xa0.y) << 2;  off[3]  = (yb0.y * W + xb0.y) << 2;
    off[4]  = (ya0.z * W + xa0.z) << 2;  off[5]  = (yb0.z * W + xb0.z) << 2;
    off[6]  = (ya0.w * W + xa0.w) << 2;  off[7]  = (yb0.w * W + xb0.w) << 2;
    off[8]  = (ya1.x * W + xa1.x) << 2;  off[9]  = (yb1.x * W + xb1.x) << 2;
    off[10] = (ya1.y * W + xa1.y) << 2;  off[11] = (yb1.y * W + xb1.y) << 2;
    off[12] = (ya1.z * W + xa1.z) << 2;  off[13] = (yb1.z * W + xb1.z) << 2;
    off[14] = (ya1.w * W + xa1.w) << 2;  off[15] = (yb1.w * W + xb1.w) << 2;

    float z[16];
    #pragma unroll
    for (int k = 0; k < 16; ++k) {
        int r = __builtin_amdgcn_raw_buffer_load_b32(rsrc, off[k], 0, /*aux sc0*/1);
        z[k] = __int_as_float(r);
    }

    // ---- phase 3: consume ----
    float acc = 0.0f;
    acc += loss_from(z[0],  z[1],  od0.x);
    acc += loss_from(z[2],  z[3],  od0.y);
    acc += loss_from(z[4],  z[5],  od0.z);
    acc += loss_from(z[6],  z[7],  od0.w);
    float acc1 = 0.0f;
    acc1 += loss_from(z[8],  z[9],  od1.x);
    acc1 += loss_from(z[10], z[11], od1.y);
    acc1 += loss_from(z[12], z[13], od1.z);
    acc1 += loss_from(z[14], z[15], od1.w);
    acc += s1 * acc1;

    // ---- wave + block reduction ----
    #pragma unroll
    for (int off2 = 32; off2 > 0; off2 >>= 1)
        acc += __shfl_down(acc, off2, 64);

    __shared__ float wsum[4];
    int lane = threadIdx.x & 63;
    int wid  = threadIdx.x >> 6;
    if (lane == 0) wsum[wid] = acc;
    __syncthreads();
    if (wid == 0 && lane == 0)
        partials[j] = wsum[0] + wsum[1] + wsum[2] + wsum[3];
}

__global__ __launch_bounds__(256) void rdc_finalize(
        const float* __restrict__ partials, float* __restrict__ out, int n) {
    float acc = 0.0f;
    for (int k = threadIdx.x; k < n; k += 256)
        acc += partials[k];
    #pragma unroll
    for (int off = 32; off > 0; off >>= 1)
        acc += __shfl_down(acc, off, 64);
    __shared__ float wsum[4];
    int lane = threadIdx.x & 63;
    int wid  = threadIdx.x >> 6;
    if (lane == 0) wsum[wid] = acc;
    __syncthreads();
    if (wid == 0 && lane == 0)
        out[0] = (wsum[0] + wsum[1] + wsum[2] + wsum[3]) * INV_N;
}

extern "C" void kernel_launch(void* const* d_in, const int* in_sizes, int n_in,
                              void* d_out, int out_size, void* d_ws, size_t ws_size,
                              hipStream_t stream) {
    const float* depth = (const float*)d_in[0];
    const vint4* xA = (const vint4*)d_in[1];
    const vint4* yA = (const vint4*)d_in[2];
    const vint4* xB = (const vint4*)d_in[3];
    const vint4* yB = (const vint4*)d_in[4];
    const vint4* ord = (const vint4*)d_in[5];
    float* out = (float*)d_out;

    float* partials = (float*)d_ws;      // NBLK*4 bytes, ws is plenty
    rdc_kernel<<<NBLK, 256, 0, stream>>>(depth, xA, yA, xB, yB, ord, partials);
    rdc_finalize<<<1, 256, 0, stream>>>(partials, out, NBLK);
}

// Round 5
// 240.794 us; speedup vs baseline: 1.0203x; 1.0048x over previous
//
#include <hip/hip_runtime.h>

// relative_depth_crit — R4: depth gathers via global_load_lds (LDS-DMA path).
// R1/R2/R3 all ~88us, insensitive to software MLP, L1 bypass, and occupancy
// => per-CU outstanding-request token cap (~48 @ ~200cyc L2 latency) on the
// VGPR-return vmem path. global_load_lds takes PER-LANE global addresses
// (scatter-gather into LDS, dest = uniform base + lane*4); if the DMA path has
// a separate/deeper token pool, the gather rate rises above 0.237 lanes/cyc/CU.

constexpr int B = 64;
constexpr int H = 512;
constexpr int W = 640;
constexpr int P = 100000;                 // divisible by 4
constexpr int N4B = P / 4;                // 25000 vec4 items per batch
constexpr int IPB = 512;                  // vec4 items per block (2 per thread)
constexpr int CHUNKS = (N4B + IPB - 1) / IPB;   // 49 blocks per batch
constexpr int NBLK = B * CHUNKS;          // 3136
constexpr float INV_N = 1.0f / (float)(B * P);
constexpr float MARGIN = 1.0f;

typedef int vint4 __attribute__((ext_vector_type(4)));

__device__ __forceinline__ float loss_from(float za, float zb, int od) {
    float zd = za - zb;
    float gt = (float)(od - 1);           // {-1, 0, 1}
    float mask = fabsf(gt);               // {0, 1}
    float t = fminf(gt * zd, MARGIN);
    float l_rank = __logf(1.0f + __expf(-t));
    float l_eq = fmaxf(zd * zd, MARGIN * MARGIN);
    return mask * l_rank + (1.0f - mask) * l_eq;
}

__global__ __launch_bounds__(256) void rdc_kernel(
        const float* __restrict__ depth,
        const vint4* __restrict__ xA, const vint4* __restrict__ yA,
        const vint4* __restrict__ xB, const vint4* __restrict__ yB,
        const vint4* __restrict__ ord,
        float* __restrict__ partials) {
    // zbuf[wave][slot][lane] — DMA dest is wave-uniform base + lane*4
    __shared__ float zbuf[4][16][64];     // 16 KB

    int j = blockIdx.x;
    // XCD-aware swizzle: j%8 ~ XCD id; each XCD sticks to batches b≡x (mod 8).
    int x = j & 7;
    int g = j >> 3;
    int b = ((g / CHUNKS) << 3) + x;
    int c = g % CHUNKS;
    int e0 = c * IPB + threadIdx.x;       // < N4B always (48*512+255=24831)
    int e1 = e0 + 256;                    // may exceed N4B only when c==48

    float s1 = (e1 < N4B) ? 1.0f : 0.0f;
    int i0 = b * N4B + e0;
    int i1 = b * N4B + (e1 < N4B ? e1 : e0);

    const float* d = depth + (size_t)b * (H * W);
    int lane = threadIdx.x & 63;
    int wid  = threadIdx.x >> 6;

    // ---- phase 1: stream index vectors (read-once -> nontemporal) ----
    vint4 xa0 = __builtin_nontemporal_load(&xA[i0]);
    vint4 ya0 = __builtin_nontemporal_load(&yA[i0]);
    vint4 xb0 = __builtin_nontemporal_load(&xB[i0]);
    vint4 yb0 = __builtin_nontemporal_load(&yB[i0]);
    vint4 od0 = __builtin_nontemporal_load(&ord[i0]);
    vint4 xa1 = __builtin_nontemporal_load(&xA[i1]);
    vint4 ya1 = __builtin_nontemporal_load(&yA[i1]);
    vint4 xb1 = __builtin_nontemporal_load(&xB[i1]);
    vint4 yb1 = __builtin_nontemporal_load(&yB[i1]);
    vint4 od1 = __builtin_nontemporal_load(&ord[i1]);

    // ---- phase 2: 16 element offsets ----
    int off[16];
    off[0]  = ya0.x * W + xa0.x;  off[1]  = yb0.x * W + xb0.x;
    off[2]  = ya0.y * W + xa0.y;  off[3]  = yb0.y * W + xb0.y;
    off[4]  = ya0.z * W + xa0.z;  off[5]  = yb0.z * W + xb0.z;
    off[6]  = ya0.w * W + xa0.w;  off[7]  = yb0.w * W + xb0.w;
    off[8]  = ya1.x * W + xa1.x;  off[9]  = yb1.x * W + xb1.x;
    off[10] = ya1.y * W + xa1.y;  off[11] = yb1.y * W + xb1.y;
    off[12] = ya1.z * W + xa1.z;  off[13] = yb1.z * W + xb1.z;
    off[14] = ya1.w * W + xa1.w;  off[15] = yb1.w * W + xb1.w;

    // ---- phase 3: 16 scattered gathers via the LDS-DMA path ----
    #pragma unroll
    for (int k = 0; k < 16; ++k) {
        __builtin_amdgcn_global_load_lds(
            (const __attribute__((address_space(1))) void*)(d + off[k]),
            (__attribute__((address_space(3))) void*)&zbuf[wid][k][0],
            4, 0, 0);
    }
    __syncthreads();   // drains vmcnt; DMA data visible in LDS

    // ---- phase 4: read back (bank = lane -> 2-way aliasing, free) ----
    float z[16];
    #pragma unroll
    for (int k = 0; k < 16; ++k)
        z[k] = zbuf[wid][k][lane];

    // ---- phase 5: consume ----
    float acc = 0.0f;
    acc += loss_from(z[0],  z[1],  od0.x);
    acc += loss_from(z[2],  z[3],  od0.y);
    acc += loss_from(z[4],  z[5],  od0.z);
    acc += loss_from(z[6],  z[7],  od0.w);
    float acc1 = 0.0f;
    acc1 += loss_from(z[8],  z[9],  od1.x);
    acc1 += loss_from(z[10], z[11], od1.y);
    acc1 += loss_from(z[12], z[13], od1.z);
    acc1 += loss_from(z[14], z[15], od1.w);
    acc += s1 * acc1;

    // ---- wave + block reduction ----
    #pragma unroll
    for (int off2 = 32; off2 > 0; off2 >>= 1)
        acc += __shfl_down(acc, off2, 64);

    __shared__ float wsum[4];
    if (lane == 0) wsum[wid] = acc;
    __syncthreads();
    if (wid == 0 && lane == 0)
        partials[j] = wsum[0] + wsum[1] + wsum[2] + wsum[3];
}

__global__ __launch_bounds__(256) void rdc_finalize(
        const float* __restrict__ partials, float* __restrict__ out, int n) {
    float acc = 0.0f;
    for (int k = threadIdx.x; k < n; k += 256)
        acc += partials[k];
    #pragma unroll
    for (int off = 32; off > 0; off >>= 1)
        acc += __shfl_down(acc, off, 64);
    __shared__ float wsum[4];
    int lane = threadIdx.x & 63;
    int wid  = threadIdx.x >> 6;
    if (lane == 0) wsum[wid] = acc;
    __syncthreads();
    if (wid == 0 && lane == 0)
        out[0] = (wsum[0] + wsum[1] + wsum[2] + wsum[3]) * INV_N;
}

extern "C" void kernel_launch(void* const* d_in, const int* in_sizes, int n_in,
                              void* d_out, int out_size, void* d_ws, size_t ws_size,
                              hipStream_t stream) {
    const float* depth = (const float*)d_in[0];
    const vint4* xA = (const vint4*)d_in[1];
    const vint4* yA = (const vint4*)d_in[2];
    const vint4* xB = (const vint4*)d_in[3];
    const vint4* yB = (const vint4*)d_in[4];
    const vint4* ord = (const vint4*)d_in[5];
    float* out = (float*)d_out;

    float* partials = (float*)d_ws;      // NBLK*4 bytes, ws is plenty
    rdc_kernel<<<NBLK, 256, 0, stream>>>(depth, xA, yA, xB, yB, ord, partials);
    rdc_finalize<<<1, 256, 0, stream>>>(partials, out, NBLK);
}